// Round 9
// baseline (304.062 us; speedup 1.0000x reference)
//
#include <hip/hip_runtime.h>

// CommLayer: y[b,a,e] = tanh( xb[b,a,:]·M[e,:] + S[b,:]·Cn[e,:] ),
//   M = H - C/7, Cn = C/7, S[b] = sum_a xb[b,a,:].
// K=128 fp16 MFMA GEMM, A_aug[m=(b,a)] = [xb | S(b)], B_aug[e] = [M[e] | Cn[e]].
// R14: R12/R13 (workspace + prep kernel + DPP) died twice in infra before
// running; can't distinguish flaky infra from a structure-induced container
// kill. This round tests the SAME phase-structure theory with a maximally
// conservative implementation -- single launch, no workspace, no DPP, no
// inline asm, i.e. structurally identical to the proven R10 kernel EXCEPT:
//   - NO LDS, NO ds_write, NO ds_read, NO BARRIER. Each lane loads its own
//     B-fragment weights directly from global (H+C = 32 KB, L1/L2-resident)
//     and converts fp32->fp16 in-register with bit-identical expressions.
//   - Waves fully decoupled: the per-block serial phase chain
//     (stage -> barrier -> DS butterfly/reads) that rounds 6-11 could not
//     reschedule away is simply gone.
// Cost: ~192 VALU ops/tile/lane of weight conversion, hidden under the
// ~900 cy HBM x-load latency (weight loads are independent of x loads).
// Kept: 8192-block churn (R10's verified win), shfl butterfly (proven).
// VGPR ~100 -> launch_bounds(256,4); measured occupancy never exceeded
// ~16 waves/CU anyway.

typedef _Float16 half8v  __attribute__((ext_vector_type(8)));
typedef float    floatx4 __attribute__((ext_vector_type(4)));

#define WAVES_PER_BLOCK 4

__device__ __forceinline__ half8v h8_bfly_add(half8v v, int mask) {
    union { half8v h; int i[4]; } u, r;
    u.h = v;
    #pragma unroll
    for (int k = 0; k < 4; ++k) r.i[k] = __shfl_xor(u.i[k], mask, 64);
    return v + r.h;   // v_pk_add_f16 x4
}

// fp32 weight pair -> (M, Cn) fp16 fragments; EXACT same arithmetic as the
// old LDS staging (m = h - c*(1/7), cn = c*(1/7), RTE casts) -> bit-identical.
__device__ __forceinline__ void cvt_mc(const float4 h0, const float4 h1,
                                       const float4 c0, const float4 c1,
                                       half8v& m, half8v& cn) {
    const float r7 = 1.0f / 7.0f;
    const float n0 = c0.x * r7, n1 = c0.y * r7, n2 = c0.z * r7, n3 = c0.w * r7;
    const float n4 = c1.x * r7, n5 = c1.y * r7, n6 = c1.z * r7, n7 = c1.w * r7;
    m[0] = (_Float16)(h0.x - n0); m[1] = (_Float16)(h0.y - n1);
    m[2] = (_Float16)(h0.z - n2); m[3] = (_Float16)(h0.w - n3);
    m[4] = (_Float16)(h1.x - n4); m[5] = (_Float16)(h1.y - n5);
    m[6] = (_Float16)(h1.z - n6); m[7] = (_Float16)(h1.w - n7);
    cn[0] = (_Float16)n0; cn[1] = (_Float16)n1;
    cn[2] = (_Float16)n2; cn[3] = (_Float16)n3;
    cn[4] = (_Float16)n4; cn[5] = (_Float16)n5;
    cn[6] = (_Float16)n6; cn[7] = (_Float16)n7;
}

__global__ __launch_bounds__(256, 4)
void comm_kernel(const float* __restrict__ x,
                 const float* __restrict__ Hw,
                 const float* __restrict__ Cw,
                 float* __restrict__ out)
{
    const int tid  = threadIdx.x;
    const int lane = tid & 63;
    const int wave = tid >> 6;
    const int quad = lane >> 4;   // 0..3
    const int l16  = lane & 15;

    const int wgid = blockIdx.x * WAVES_PER_BLOCK + wave;   // one m-tile per wave
    const float* xi = x + (size_t)wgid * 1024 + l16 * 64 + quad * 8;
    float* o = out + (size_t)wgid * 1024 + l16 * 64 + quad * 4;

    // ---- x loads (HBM, ~900 cy) ----
    const float4 v0 = *reinterpret_cast<const float4*>(xi);
    const float4 v1 = *reinterpret_cast<const float4*>(xi + 4);
    const float4 v2 = *reinterpret_cast<const float4*>(xi + 32);
    const float4 v3 = *reinterpret_cast<const float4*>(xi + 36);

    // ---- x fragments (B-operand layout: n = l16, k = quad*8 + j) ----
    half8v a0, a1;   // kt=0 (k 0..31), kt=1 (k 32..63)
    a0[0]=(_Float16)v0.x; a0[1]=(_Float16)v0.y; a0[2]=(_Float16)v0.z; a0[3]=(_Float16)v0.w;
    a0[4]=(_Float16)v1.x; a0[5]=(_Float16)v1.y; a0[6]=(_Float16)v1.z; a0[7]=(_Float16)v1.w;
    a1[0]=(_Float16)v2.x; a1[1]=(_Float16)v2.y; a1[2]=(_Float16)v2.z; a1[3]=(_Float16)v2.w;
    a1[4]=(_Float16)v3.x; a1[5]=(_Float16)v3.y; a1[6]=(_Float16)v3.z; a1[7]=(_Float16)v3.w;

    // ---- S via packed fp16 butterfly over the 8 agent-lanes (l16 bits 0..2).
    // Result broadcast to every lane = kt=2,3 augmented fragment. ----
    half8v s0 = a0, s1 = a1;
    #pragma unroll
    for (int m = 1; m <= 4; m <<= 1) {
        s0 = h8_bfly_add(s0, m);
        s1 = h8_bfly_add(s1, m);
    }

    // ---- MFMA, transposed: weights as A-operand, loaded per-lane straight
    // from global (L1/L2-resident 32 KB) and converted in-register. ----
    floatx4 acc[4];
    #pragma unroll
    for (int nt = 0; nt < 4; ++nt) acc[nt] = floatx4{0.f, 0.f, 0.f, 0.f};

    #pragma unroll
    for (int nt = 0; nt < 4; ++nt) {
        const int e = nt * 16 + l16;                 // weight row this lane needs
        const float* Hp = Hw + e * 64 + quad * 8;
        const float* Cp = Cw + e * 64 + quad * 8;
        const float4 h00 = *reinterpret_cast<const float4*>(Hp);
        const float4 h01 = *reinterpret_cast<const float4*>(Hp + 4);
        const float4 h10 = *reinterpret_cast<const float4*>(Hp + 32);
        const float4 h11 = *reinterpret_cast<const float4*>(Hp + 36);
        const float4 c00 = *reinterpret_cast<const float4*>(Cp);
        const float4 c01 = *reinterpret_cast<const float4*>(Cp + 4);
        const float4 c10 = *reinterpret_cast<const float4*>(Cp + 32);
        const float4 c11 = *reinterpret_cast<const float4*>(Cp + 36);

        half8v b0, b1, b2, b3;                       // M lo/hi, Cn lo/hi
        cvt_mc(h00, h01, c00, c01, b0, b2);
        cvt_mc(h10, h11, c10, c11, b1, b3);

        acc[nt] = __builtin_amdgcn_mfma_f32_16x16x32_f16(b0, a0, acc[nt], 0, 0, 0);
        acc[nt] = __builtin_amdgcn_mfma_f32_16x16x32_f16(b1, a1, acc[nt], 0, 0, 0);
        acc[nt] = __builtin_amdgcn_mfma_f32_16x16x32_f16(b2, s0, acc[nt], 0, 0, 0);
        acc[nt] = __builtin_amdgcn_mfma_f32_16x16x32_f16(b3, s1, acc[nt], 0, 0, 0);
    }

    // ---- Epilogue: C/D col = l16 = agent-row, row = quad*4+reg = e offset.
    // Lane writes 16B at l16*256B + nt*64B + quad*16B: quads form 64B runs,
    // nt pairs complete 128B lines -> L2 merges (plain stores). ----
    #pragma unroll
    for (int nt = 0; nt < 4; ++nt) {
        floatx4 r;
        #pragma unroll
        for (int reg = 0; reg < 4; ++reg) {
            float y = acc[nt][reg];
            y = fminf(10.f, fmaxf(-10.f, y));
            const float tv  = __builtin_amdgcn_exp2f(y * 2.8853900817779268f); // e^{2y}
            r[reg] = (tv - 1.f) * __builtin_amdgcn_rcpf(tv + 1.f);
        }
        *reinterpret_cast<floatx4*>(o + nt * 16) = r;
    }
}

extern "C" void kernel_launch(void* const* d_in, const int* in_sizes, int n_in,
                              void* d_out, int out_size, void* d_ws, size_t ws_size,
                              hipStream_t stream) {
    const float* x  = (const float*)d_in[0];
    const float* Hw = (const float*)d_in[1];
    const float* Cw = (const float*)d_in[2];
    float* out = (float*)d_out;

    const int rows   = in_sizes[0] / 512;        // 65536 batch rows
    const int ntiles = rows * 8 / 16;            // 32768 m-tiles
    const int blocks = ntiles / WAVES_PER_BLOCK; // 8192 blocks, 1 tile/wave
    comm_kernel<<<blocks, 256, 0, stream>>>(x, Hw, Cw, out);
}

// Round 10
// 235.709 us; speedup vs baseline: 1.2900x; 1.2900x over previous
//
#include <hip/hip_runtime.h>

// CommLayer: y[b,a,e] = tanh( xb[b,a,:]·M[e,:] + S[b,:]·Cn[e,:] ),
//   M = H - C/7, Cn = C/7, S[b] = sum_a xb[b,a,:].
// K=128 fp16 MFMA GEMM, A_aug[m=(b,a)] = [xb | S(b)], B_aug[e] = [M[e] | Cn[e]].
// R15: R14 (no-LDS, weights from L1 per tile) regressed 70->150us with the
// session's HIGHEST occupancy (70%) -- TLP is not the limiter and the LDS
// apparatus is not the cost. New theory: WORKGROUP DISPATCH RATE. R10 retired
// 8192 blocks in ~70us = 117 blocks/us ~= the command processor's dispatch
// ceiling; CUs are starved for blocks (explains low 38-50% occupancy in
// R0-R9 and why within-wave scheduling never mattered). Test: identical
// per-wave work and churn-generation count, HALF the dispatches -- block
// 256->512 (8 waves), 4096 blocks, stage loop 4->2 iterations. Everything
// else is R10 verbatim.
// Prediction: dispatch-bound -> comm ~40-55us (dur 195-212); flat -> test
// 1024-thread blocks next, then mixed-stream probe.

typedef _Float16 half4v  __attribute__((ext_vector_type(4)));
typedef _Float16 half8v  __attribute__((ext_vector_type(8)));
typedef float    floatx4 __attribute__((ext_vector_type(4)));

#define BLOCK_THREADS   512
#define WAVES_PER_BLOCK 8
#define BSTRIDE 144   // halfs per augB row: 128 + 16 pad (288 B = 32 mod 128)

__device__ __forceinline__ half8v h8_bfly_add(half8v v, int mask) {
    union { half8v h; int i[4]; } u, r;
    u.h = v;
    #pragma unroll
    for (int k = 0; k < 4; ++k) r.i[k] = __shfl_xor(u.i[k], mask, 64);
    return v + r.h;   // v_pk_add_f16 x4
}

__global__ __launch_bounds__(BLOCK_THREADS, 8)
void comm_kernel(const float* __restrict__ x,
                 const float* __restrict__ Hw,
                 const float* __restrict__ Cw,
                 float* __restrict__ out)
{
    __shared__ __align__(16) _Float16 augB[64 * BSTRIDE];  // 18432 B

    const int tid  = threadIdx.x;
    const int lane = tid & 63;
    const int wave = tid >> 6;
    const int quad = lane >> 4;   // 0..3
    const int l16  = lane & 15;

    // ---- Stage 0 (once per block): build augmented B in LDS ----
    // augB[e][k<64] = H[e][k] - C[e][k]/7 ; augB[e][64+k] = C[e][k]/7
    #pragma unroll
    for (int i = 0; i < 2; ++i) {
        const int idx = i * BLOCK_THREADS + tid;   // 0..1023 float4-chunks
        const int e = idx >> 4;
        const int k = (idx & 15) << 2;
        const float4 h = *reinterpret_cast<const float4*>(Hw + e * 64 + k);
        const float4 c = *reinterpret_cast<const float4*>(Cw + e * 64 + k);
        half4v m4, c4;
        m4[0] = (_Float16)(h.x - c.x * (1.0f / 7.0f)); c4[0] = (_Float16)(c.x * (1.0f / 7.0f));
        m4[1] = (_Float16)(h.y - c.y * (1.0f / 7.0f)); c4[1] = (_Float16)(c.y * (1.0f / 7.0f));
        m4[2] = (_Float16)(h.z - c.z * (1.0f / 7.0f)); c4[2] = (_Float16)(c.z * (1.0f / 7.0f));
        m4[3] = (_Float16)(h.w - c.w * (1.0f / 7.0f)); c4[3] = (_Float16)(c.w * (1.0f / 7.0f));
        *reinterpret_cast<half4v*>(&augB[e * BSTRIDE + k])      = m4;
        *reinterpret_cast<half4v*>(&augB[e * BSTRIDE + 64 + k]) = c4;
    }
    __syncthreads();   // the only barrier

    const int wgid = blockIdx.x * WAVES_PER_BLOCK + wave;   // one m-tile per wave
    const float* xi = x + (size_t)wgid * 1024 + l16 * 64 + quad * 8;
    float* o = out + (size_t)wgid * 1024 + l16 * 64 + quad * 4;

    // ---- One tile: 4 loads -> convert -> butterfly -> MFMA -> store ----
    const float4 v0 = *reinterpret_cast<const float4*>(xi);
    const float4 v1 = *reinterpret_cast<const float4*>(xi + 4);
    const float4 v2 = *reinterpret_cast<const float4*>(xi + 32);
    const float4 v3 = *reinterpret_cast<const float4*>(xi + 36);

    // ---- x fragments (B-operand layout: n = l16, k = quad*8 + j) ----
    half8v a0, a1;   // kt=0 (k 0..31), kt=1 (k 32..63)
    a0[0]=(_Float16)v0.x; a0[1]=(_Float16)v0.y; a0[2]=(_Float16)v0.z; a0[3]=(_Float16)v0.w;
    a0[4]=(_Float16)v1.x; a0[5]=(_Float16)v1.y; a0[6]=(_Float16)v1.z; a0[7]=(_Float16)v1.w;
    a1[0]=(_Float16)v2.x; a1[1]=(_Float16)v2.y; a1[2]=(_Float16)v2.z; a1[3]=(_Float16)v2.w;
    a1[4]=(_Float16)v3.x; a1[5]=(_Float16)v3.y; a1[6]=(_Float16)v3.z; a1[7]=(_Float16)v3.w;

    // ---- S via packed fp16 butterfly over the 8 agent-lanes (l16 bits 0..2).
    // Result is broadcast to every lane = kt=2,3 augmented fragment. ----
    half8v s0 = a0, s1 = a1;
    #pragma unroll
    for (int m = 1; m <= 4; m <<= 1) {
        s0 = h8_bfly_add(s0, m);
        s1 = h8_bfly_add(s1, m);
    }

    // ---- MFMA, transposed: weights as A-operand ----
    floatx4 acc[4];
    #pragma unroll
    for (int nt = 0; nt < 4; ++nt) acc[nt] = floatx4{0.f, 0.f, 0.f, 0.f};

    #pragma unroll
    for (int nt = 0; nt < 4; ++nt) {
        const _Float16* bp = &augB[(nt * 16 + l16) * BSTRIDE + quad * 8];
        const half8v b0 = *reinterpret_cast<const half8v*>(bp);
        const half8v b1 = *reinterpret_cast<const half8v*>(bp + 32);
        const half8v b2 = *reinterpret_cast<const half8v*>(bp + 64);
        const half8v b3 = *reinterpret_cast<const half8v*>(bp + 96);
        acc[nt] = __builtin_amdgcn_mfma_f32_16x16x32_f16(b0, a0, acc[nt], 0, 0, 0);
        acc[nt] = __builtin_amdgcn_mfma_f32_16x16x32_f16(b1, a1, acc[nt], 0, 0, 0);
        acc[nt] = __builtin_amdgcn_mfma_f32_16x16x32_f16(b2, s0, acc[nt], 0, 0, 0);
        acc[nt] = __builtin_amdgcn_mfma_f32_16x16x32_f16(b3, s1, acc[nt], 0, 0, 0);
    }

    // ---- Epilogue: C/D col = l16 = agent-row, row = quad*4+reg = e offset.
    // Lane writes 16B at l16*256B + nt*64B + quad*16B: quads form 64B runs,
    // nt pairs complete 128B lines -> L2 merges (plain stores). ----
    #pragma unroll
    for (int nt = 0; nt < 4; ++nt) {
        floatx4 r;
        #pragma unroll
        for (int reg = 0; reg < 4; ++reg) {
            float y = acc[nt][reg];
            y = fminf(10.f, fmaxf(-10.f, y));
            const float tv  = __builtin_amdgcn_exp2f(y * 2.8853900817779268f); // e^{2y}
            r[reg] = (tv - 1.f) * __builtin_amdgcn_rcpf(tv + 1.f);
        }
        *reinterpret_cast<floatx4*>(o + nt * 16) = r;
    }
}

extern "C" void kernel_launch(void* const* d_in, const int* in_sizes, int n_in,
                              void* d_out, int out_size, void* d_ws, size_t ws_size,
                              hipStream_t stream) {
    const float* x  = (const float*)d_in[0];
    const float* Hw = (const float*)d_in[1];
    const float* Cw = (const float*)d_in[2];
    float* out = (float*)d_out;

    const int rows   = in_sizes[0] / 512;        // 65536 batch rows
    const int ntiles = rows * 8 / 16;            // 32768 m-tiles
    const int blocks = ntiles / WAVES_PER_BLOCK; // 4096 blocks, 1 tile/wave
    comm_kernel<<<blocks, BLOCK_THREADS, 0, stream>>>(x, Hw, Cw, out);
}